// Round 10
// baseline (348.312 us; speedup 1.0000x reference)
//
#include <hip/hip_runtime.h>
#include <cstddef>

static constexpr int Bb = 64;     // batch
static constexpr int Nn = 256;    // nodes
static constexpr int Td = 512;    // time dim
static constexpr int NMAXS = 51;  // 256 // 5
static constexpr float EPSN = 1e-5f;
static constexpr float EPSD = 1e-10f;

typedef unsigned short u16;
typedef __attribute__((ext_vector_type(8))) short short8;
typedef __attribute__((ext_vector_type(4))) float f32x4;

__device__ __forceinline__ u16 f2b(float f) {
    unsigned u = __float_as_uint(f);
    return (u16)((u + 0x7fffu + ((u >> 16) & 1u)) >> 16);
}
__device__ __forceinline__ float b2f(u16 h) {
    return __uint_as_float(((unsigned)h) << 16);
}
__device__ __forceinline__ float4 unp2(uint2 h, uint2 l) {
    float4 r;
    r.x = b2f((u16)h.x) + b2f((u16)l.x);
    r.y = b2f((u16)(h.x >> 16)) + b2f((u16)(l.x >> 16));
    r.z = b2f((u16)h.y) + b2f((u16)l.y);
    r.w = b2f((u16)(h.y >> 16)) + b2f((u16)(l.y >> 16));
    return r;
}

// async global->LDS DMA, 16B/lane. LDS dest = wave-uniform base + lane*16.
__device__ __forceinline__ void gload_lds(const u16* g, u16* l) {
    __builtin_amdgcn_global_load_lds(
        (const __attribute__((address_space(1))) unsigned int*)g,
        (__attribute__((address_space(3))) unsigned int*)l, 16, 0, 0);
}
__device__ __forceinline__ int swz4(int r) { return (r ^ (r >> 2)) & 3; }

// ---------------- LayerNorm stats stage A ----------------
__global__ __launch_bounds__(256) void ln_partial_k(const float4* __restrict__ x,
                                                    float2* __restrict__ part) {
    int b = blockIdx.y, c = blockIdx.x;
    int base = b * 32768 + c * 1024;
    float s = 0.f, s2 = 0.f;
#pragma unroll
    for (int j = 0; j < 4; ++j) {
        float4 v = x[base + j * 256 + threadIdx.x];
        s += v.x + v.y + v.z + v.w;
        s2 += v.x * v.x + v.y * v.y + v.z * v.z + v.w * v.w;
    }
    __shared__ float sh[256], sh2[256];
    sh[threadIdx.x] = s; sh2[threadIdx.x] = s2;
    __syncthreads();
    for (int o = 128; o > 0; o >>= 1) {
        if (threadIdx.x < o) { sh[threadIdx.x] += sh[threadIdx.x + o]; sh2[threadIdx.x] += sh2[threadIdx.x + o]; }
        __syncthreads();
    }
    if (threadIdx.x == 0) part[b * 32 + c] = make_float2(sh[0], sh2[0]);
}

// LN apply (finalize fused via shfl over 32 partials): hi/lo bf16 split out
__global__ __launch_bounds__(256) void ln_apply_split_k(const float4* __restrict__ x,
                                                        const float4* __restrict__ w,
                                                        const float4* __restrict__ bia,
                                                        const float2* __restrict__ part,
                                                        uint2* __restrict__ xhi,
                                                        uint2* __restrict__ xlo) {
    int i = blockIdx.x * 256 + threadIdx.x;
    int r = i & ((Nn * Td / 4) - 1);
    int b = i >> 15;
    float2 p = part[b * 32 + (threadIdx.x & 31)];
    float s = p.x, s2 = p.y;
#pragma unroll
    for (int o = 16; o > 0; o >>= 1) { s += __shfl_xor(s, o, 32); s2 += __shfl_xor(s2, o, 32); }
    float inv = 1.f / (Nn * Td);
    float mu = s * inv;
    float var = s2 * inv - mu * mu;
    float rs = rsqrtf(var + EPSN);
    float4 xv = x[i], wv = w[r], bv = bia[r];
    float4 o;
    o.x = (xv.x - mu) * rs * wv.x + bv.x;
    o.y = (xv.y - mu) * rs * wv.y + bv.y;
    o.z = (xv.z - mu) * rs * wv.z + bv.z;
    o.w = (xv.w - mu) * rs * wv.w + bv.w;
    u16 hx = f2b(o.x), hy = f2b(o.y), hz = f2b(o.z), hw = f2b(o.w);
    uint2 ph, pl;
    ph.x = (unsigned)hx | ((unsigned)hy << 16);
    ph.y = (unsigned)hz | ((unsigned)hw << 16);
    pl.x = (unsigned)f2b(o.x - b2f(hx)) | ((unsigned)f2b(o.y - b2f(hy)) << 16);
    pl.y = (unsigned)f2b(o.z - b2f(hz)) | ((unsigned)f2b(o.w - b2f(hw)) << 16);
    xhi[i] = ph;
    xlo[i] = pl;
}

// ---------------- param prep: cheb_w^T -> bWc (z<3) ; li_w hi/lo split (z==3) ----------------
__global__ __launch_bounds__(256) void param_prep_k(const float* __restrict__ cheb_w,
                                                    u16* __restrict__ bWc,
                                                    const float* __restrict__ li_w,
                                                    u16* __restrict__ liwhi,
                                                    u16* __restrict__ liwlo) {
    int z = blockIdx.z;
    int c0 = blockIdx.x * 32, r0 = blockIdx.y * 32;
    int tx = threadIdx.x & 31, ty = threadIdx.x >> 5;
    if (z < 3) {
        __shared__ u16 tile[32][33];
        const float* ip = cheb_w + (size_t)z * Td * Td;
#pragma unroll
        for (int i = 0; i < 4; ++i) {
            int r = ty + i * 8;
            tile[r][tx] = f2b(ip[(size_t)(r0 + r) * Td + c0 + tx]);
        }
        __syncthreads();
#pragma unroll
        for (int i = 0; i < 4; ++i) {
            int c = ty + i * 8;
            bWc[(size_t)(c0 + c) * 1536 + z * 512 + (r0 + tx)] = tile[tx][c];
        }
    } else {
#pragma unroll
        for (int i = 0; i < 4; ++i) {
            int r = r0 + ty + i * 8;
            size_t idx = (size_t)r * Td + c0 + tx;
            float v = li_w[idx];
            u16 h = f2b(v);
            liwhi[idx] = h;
            liwlo[idx] = f2b(v - b2f(h));
        }
    }
}

// ---------------- BatchNorm stats stage A (from hi/lo split) ----------------
__global__ __launch_bounds__(256) void bn_partial_k(const uint2* __restrict__ xhi,
                                                    const uint2* __restrict__ xlo,
                                                    float2* __restrict__ part) {
    int n = blockIdx.y, c = blockIdx.x;
    float s = 0.f, s2 = 0.f;
#pragma unroll
    for (int j = 0; j < 4; ++j) {
        int f = j * 256 + threadIdx.x;
        int bl = f >> 7, t4 = f & 127;
        size_t idx = ((size_t)(c * 8 + bl) * Nn + n) * 128 + t4;
        float4 v = unp2(xhi[idx], xlo[idx]);
        s += v.x + v.y + v.z + v.w;
        s2 += v.x * v.x + v.y * v.y + v.z * v.z + v.w * v.w;
    }
    __shared__ float sh[256], sh2[256];
    sh[threadIdx.x] = s; sh2[threadIdx.x] = s2;
    __syncthreads();
    for (int o = 128; o > 0; o >>= 1) {
        if (threadIdx.x < o) { sh[threadIdx.x] += sh[threadIdx.x + o]; sh2[threadIdx.x] += sh2[threadIdx.x + o]; }
        __syncthreads();
    }
    if (threadIdx.x == 0) part[n * 8 + c] = make_float2(sh[0], sh2[0]);
}

// BN apply (finalize fused via shfl over 8 partials); writes Tx0 bf16 into cat[.,0:512]
__global__ __launch_bounds__(256) void bn_apply_cast_k(const uint2* __restrict__ xhi,
                                                       const uint2* __restrict__ xlo,
                                                       const float2* __restrict__ part,
                                                       const float* __restrict__ g,
                                                       const float* __restrict__ be,
                                                       uint2* __restrict__ cat) {
    int i = blockIdx.x * 256 + threadIdx.x;   // uint2 index over BNT/4
    int row = i >> 7, c4 = i & 127;
    int n = row & 255;
    float2 p = part[n * 8 + (threadIdx.x & 7)];
    float s = p.x, s2 = p.y;
#pragma unroll
    for (int o = 4; o > 0; o >>= 1) { s += __shfl_xor(s, o, 8); s2 += __shfl_xor(s2, o, 8); }
    float inv = 1.f / (Bb * Td);
    float mu = s * inv;
    float var = s2 * inv - mu * mu;
    float rs = rsqrtf(var + EPSN);
    float scale = rs * g[n];
    float shift = be[n] - mu * scale;
    float4 v = unp2(xhi[i], xlo[i]);
    v.x = v.x * scale + shift; v.y = v.y * scale + shift;
    v.z = v.z * scale + shift; v.w = v.w * scale + shift;
    uint2 o2;
    o2.x = (unsigned)f2b(v.x) | ((unsigned)f2b(v.y) << 16);
    o2.y = (unsigned)f2b(v.z) | ((unsigned)f2b(v.w) << 16);
    cat[(size_t)row * 384 + c4] = o2;   // 1536 u16 = 384 uint2 per row
}

// ---------------- top-k radix-select + adjacency; writes bf16 A + dinv ----------------
__global__ __launch_bounds__(256) void topk_sel_k(const float* __restrict__ sc,
                                                  const float* __restrict__ dis,
                                                  u16* __restrict__ bA,
                                                  float* __restrict__ dinv) {
    int row = blockIdx.x;
    int n = row & 255;
    int tid = threadIdx.x;
    int lane = tid & 63, wv = tid >> 6;
    const float* srow = sc + (size_t)row * Nn;
    float v = srow[tid];
    unsigned fu = __float_as_uint(v);
    unsigned key = (fu & 0x80000000u) ? ~fu : (fu | 0x80000000u);
    __shared__ int hist[256];
    __shared__ int cum[256];
    __shared__ unsigned sh_pref;
    __shared__ int sh_rank;
    __shared__ float wsum[4];
    if (tid == 0) { sh_pref = 0u; sh_rank = Nn - NMAXS; }  // 205
    __syncthreads();
#pragma unroll
    for (int shift = 24; shift >= 0; shift -= 8) {
        unsigned mhi = (shift == 24) ? 0u : (0xFFFFFFFFu << (shift + 8));
        unsigned pref = sh_pref;
        int rank = sh_rank;
        hist[tid] = 0;
        __syncthreads();
        if ((key & mhi) == pref) atomicAdd(&hist[(key >> shift) & 255], 1);
        __syncthreads();
        if (tid < 64) {
            int4 h = *(const int4*)&hist[tid * 4];
            int s0 = h.x, s1 = s0 + h.y, s2 = s1 + h.z, s3 = s2 + h.w;
            int t = s3;
#pragma unroll
            for (int o = 1; o < 64; o <<= 1) { int y = __shfl_up(t, o, 64); if (lane >= o) t += y; }
            int excl = t - s3;
            cum[tid * 4]     = excl + s0;
            cum[tid * 4 + 1] = excl + s1;
            cum[tid * 4 + 2] = excl + s2;
            cum[tid * 4 + 3] = excl + s3;
        }
        __syncthreads();
        int below = (tid == 0) ? 0 : cum[tid - 1];
        if (cum[tid] > rank && below <= rank) {
            sh_pref = pref | ((unsigned)tid << shift);
            sh_rank = rank - below;
        }
        __syncthreads();
    }
    unsigned kk = sh_pref;
    float kth = __uint_as_float((kk & 0x80000000u) ? (kk & 0x7FFFFFFFu) : ~kk);
    float as = (v >= kth) ? v : 0.f;
    float a = fmaxf(as + dis[(size_t)n * Nn + tid], 0.f);
    bA[(size_t)row * Nn + tid] = f2b(a);
    float s = a;
#pragma unroll
    for (int o = 32; o > 0; o >>= 1) s += __shfl_down(s, o, 64);
    if (lane == 0) wsum[wv] = s;
    __syncthreads();
    if (tid == 0) dinv[row] = rsqrtf(wsum[0] + wsum[1] + wsum[2] + wsum[3] + EPSD);
}

// ---------------- transpose u16 (+per-input-row scale) ----------------
__global__ __launch_bounds__(256) void tscale_k(const u16* __restrict__ in,
                                                u16* __restrict__ out,
                                                long long ibz, int ildr,
                                                long long obz, int oldr,
                                                const float* __restrict__ rs, int rsz) {
    __shared__ u16 tile[32][33];
    int b = blockIdx.z;
    int c0 = blockIdx.x * 32, r0 = blockIdx.y * 32;
    int tx = threadIdx.x & 31, ty = threadIdx.x >> 5;
#pragma unroll
    for (int i = 0; i < 4; ++i) {
        int r = ty + i * 8;
        float f = b2f(in[(size_t)b * ibz + (size_t)(r0 + r) * ildr + c0 + tx]);
        f *= rs[b * rsz + r0 + r];
        tile[r][tx] = f2b(f);
    }
    __syncthreads();
#pragma unroll
    for (int i = 0; i < 4; ++i) {
        int c = ty + i * 8;
        out[(size_t)b * obz + (size_t)(c0 + c) * oldr + (r0 + tx)] = tile[tx][c];
    }
}

// ---------------- bf16 MFMA GEMM, NT, BK=64 ----------------
// A: LDS DMA double-buffer. B: DIRECT global->VGPR fragments (coalesced: lanes
// {l,l+16,l+32,l+48} cover one 64B line), register ping-pong one iter ahead.
// LDS reads per block-iter halve vs staging B. MFMA order unchanged -> bit-identical.
template <bool FINAL, bool SUBPREV, bool RSCALE, bool WF32, bool WBF>
__global__ __launch_bounds__(256) void gemm_bf_k(const u16* __restrict__ A,
                                                 const u16* __restrict__ Bt,
                                                 const float* __restrict__ bias,
                                                 const u16* __restrict__ prevb, int ldprev,
                                                 float* __restrict__ C,
                                                 u16* __restrict__ Cb, int ldcb,
                                                 const float* __restrict__ rscale, int rsz,
                                                 float alpha, int Ncols, int K,
                                                 long long sA, long long sB, long long sPrev,
                                                 long long sC, long long sCb) {
    __shared__ u16 As[2][8192];   // [buf][h*4096 + row*32 + swizzled chunk]
    int z = blockIdx.z;
    const u16* Ag = A + (size_t)z * sA;
    const u16* Bg = Bt + (size_t)z * sB;
    int br = blockIdx.x * 128, bc = blockIdx.y * 128;
    int tid = threadIdx.x, lane = tid & 63, wave = tid >> 6;
    int wr = (wave >> 1) * 64, wc = (wave & 1) * 64;
    int i0 = wave * 2;
    int rl0 = i0 * 16 + (lane >> 2);
    int rl1 = rl0 + 16;
    int cp = lane & 3;
    int ca0 = (cp ^ swz4(rl0)) * 8;
    int ca1 = (cp ^ swz4(rl1)) * 8;
    const u16* gA0 = Ag + (size_t)(br + rl0) * K + ca0;
    const u16* gA1 = Ag + (size_t)(br + rl1) * K + ca1;
    f32x4 acc[4][4] = {};
    int fr = lane & 15, fq = lane >> 4;
    // B fragment row pointers (per ni), k-chunk fq*8
    const u16* gBf[4];
#pragma unroll
    for (int ni = 0; ni < 4; ++ni)
        gBf[ni] = Bg + (size_t)(bc + wc + ni * 16 + fr) * K + fq * 8;
    auto stageA = [&](int buf, int k0) {
#pragma unroll
        for (int h = 0; h < 2; ++h) {
            int kk = k0 + h * 32;
            int ho = h * 4096;
            gload_lds(gA0 + kk, &As[buf][ho + i0 * 512]);
            gload_lds(gA1 + kk, &As[buf][ho + i0 * 512 + 512]);
        }
    };
    short8 b0[2][4], b1[2][4];
    auto loadB = [&](int k0, short8 bf[2][4]) {
#pragma unroll
        for (int h = 0; h < 2; ++h)
#pragma unroll
            for (int ni = 0; ni < 4; ++ni)
                bf[h][ni] = *(const short8*)(gBf[ni] + k0 + h * 32);
    };
    auto compute = [&](int buf, short8 bf[2][4]) {
#pragma unroll
        for (int h = 0; h < 2; ++h) {
            int ho = h * 4096;
            short8 af[4];
#pragma unroll
            for (int mi = 0; mi < 4; ++mi) {
                int rr = wr + mi * 16 + fr;
                af[mi] = *(const short8*)&As[buf][ho + rr * 32 + ((fq ^ swz4(rr)) << 3)];
            }
#pragma unroll
            for (int mi = 0; mi < 4; ++mi)
#pragma unroll
                for (int ni = 0; ni < 4; ++ni)
                    acc[mi][ni] = __builtin_amdgcn_mfma_f32_16x16x32_bf16(af[mi], bf[h][ni], acc[mi][ni], 0, 0, 0);
        }
    };
    int nIter = K >> 6;   // all call sites have nIter even
    stageA(0, 0);
    loadB(0, b0);
    for (int it = 0; it < nIter; it += 2) {
        __syncthreads();                        // drains stageA issued one compute-phase ago
        if (it + 1 < nIter) { stageA(1, (it + 1) << 6); loadB((it + 1) << 6, b1); }
        compute(0, b0);
        __syncthreads();
        if (it + 2 < nIter) { stageA(0, (it + 2) << 6); loadB((it + 2) << 6, b0); }
        compute(1, b1);
    }
    const u16* Pp = SUBPREV ? prevb + (size_t)z * sPrev : nullptr;
    float* Cp = WF32 ? C + (size_t)z * sC : nullptr;
    u16* Cbp = WBF ? Cb + (size_t)z * sCb : nullptr;
    const float* rsp = RSCALE ? rscale + (size_t)z * rsz : nullptr;
#pragma unroll
    for (int mi = 0; mi < 4; ++mi) {
#pragma unroll
        for (int rg = 0; rg < 4; ++rg) {
            int row = br + wr + mi * 16 + fq * 4 + rg;
            float rowsc = RSCALE ? rsp[row] : 1.f;
#pragma unroll
            for (int ni = 0; ni < 4; ++ni) {
                int col = bc + wc + ni * 16 + fr;
                float v = alpha * acc[mi][ni][rg];
                if (RSCALE) v *= rowsc;
                if (SUBPREV) v -= b2f(Pp[(size_t)row * ldprev + col]);
                if (FINAL) v = fmaxf(v + bias[col], 0.f);
                if (WF32) Cp[(size_t)row * Ncols + col] = v;
                if (WBF) Cbp[(size_t)row * ldcb + col] = f2b(v);
            }
        }
    }
}

// ---------------- split-bf16 3-MFMA GEMM, NT, BK=32; A in LDS, B direct ----------------
template <bool BIAS, bool WSPLIT, bool WF32>
__global__ __launch_bounds__(256) void gemm_bf3_k(const u16* __restrict__ Ahi,
                                                  const u16* __restrict__ Alo,
                                                  const u16* __restrict__ Bhi,
                                                  const u16* __restrict__ Blo,
                                                  const float* __restrict__ bias,
                                                  float* __restrict__ C,
                                                  u16* __restrict__ Chi,
                                                  u16* __restrict__ Clo,
                                                  int Ncols, int K,
                                                  long long sA, long long sB, long long sC) {
    __shared__ u16 Ash[2][4096];
    __shared__ u16 Asl[2][4096];
    int z = blockIdx.z;
    const u16* Agh = Ahi + (size_t)z * sA;
    const u16* Agl = Alo + (size_t)z * sA;
    const u16* Bgh = Bhi + (size_t)z * sB;
    const u16* Bgl = Blo + (size_t)z * sB;
    int br = blockIdx.x * 128, bc = blockIdx.y * 128;
    int tid = threadIdx.x, lane = tid & 63, wave = tid >> 6;
    int wr = (wave >> 1) * 64, wc = (wave & 1) * 64;
    int i0 = wave * 2;
    int rl0 = i0 * 16 + (lane >> 2);
    int rl1 = rl0 + 16;
    int cp = lane & 3;
    int ca0 = (cp ^ swz4(rl0)) * 8;
    int ca1 = (cp ^ swz4(rl1)) * 8;
    size_t oA0 = (size_t)(br + rl0) * K + ca0;
    size_t oA1 = (size_t)(br + rl1) * K + ca1;
    f32x4 acc[4][4] = {};
    int fr = lane & 15, fq = lane >> 4;
    const u16* gBh[4];
    const u16* gBl[4];
#pragma unroll
    for (int ni = 0; ni < 4; ++ni) {
        size_t o = (size_t)(bc + wc + ni * 16 + fr) * K + fq * 8;
        gBh[ni] = Bgh + o;
        gBl[ni] = Bgl + o;
    }
    auto stageA = [&](int buf, int kk) {
        gload_lds(Agh + oA0 + kk, &Ash[buf][i0 * 512]);
        gload_lds(Agh + oA1 + kk, &Ash[buf][i0 * 512 + 512]);
        gload_lds(Agl + oA0 + kk, &Asl[buf][i0 * 512]);
        gload_lds(Agl + oA1 + kk, &Asl[buf][i0 * 512 + 512]);
    };
    short8 bh0[4], bl0[4], bh1[4], bl1[4];
    auto loadB = [&](int kk, short8 bh[4], short8 bl[4]) {
#pragma unroll
        for (int ni = 0; ni < 4; ++ni) {
            bh[ni] = *(const short8*)(gBh[ni] + kk);
            bl[ni] = *(const short8*)(gBl[ni] + kk);
        }
    };
    auto compute = [&](int buf, short8 bh[4], short8 bl[4]) {
        short8 afh[4], afl[4];
#pragma unroll
        for (int mi = 0; mi < 4; ++mi) {
            int rr = wr + mi * 16 + fr;
            int off = rr * 32 + ((fq ^ swz4(rr)) << 3);
            afh[mi] = *(const short8*)&Ash[buf][off];
            afl[mi] = *(const short8*)&Asl[buf][off];
        }
#pragma unroll
        for (int mi = 0; mi < 4; ++mi)
#pragma unroll
            for (int ni = 0; ni < 4; ++ni) {
                acc[mi][ni] = __builtin_amdgcn_mfma_f32_16x16x32_bf16(afh[mi], bh[ni], acc[mi][ni], 0, 0, 0);
                acc[mi][ni] = __builtin_amdgcn_mfma_f32_16x16x32_bf16(afh[mi], bl[ni], acc[mi][ni], 0, 0, 0);
                acc[mi][ni] = __builtin_amdgcn_mfma_f32_16x16x32_bf16(afl[mi], bh[ni], acc[mi][ni], 0, 0, 0);
            }
    };
    int nIter = K >> 5;   // 16 at both call sites (even)
    stageA(0, 0);
    loadB(0, bh0, bl0);
    for (int it = 0; it < nIter; it += 2) {
        __syncthreads();
        if (it + 1 < nIter) { stageA(1, (it + 1) << 5); loadB((it + 1) << 5, bh1, bl1); }
        compute(0, bh0, bl0);
        __syncthreads();
        if (it + 2 < nIter) { stageA(0, (it + 2) << 5); loadB((it + 2) << 5, bh0, bl0); }
        compute(1, bh1, bl1);
    }
    float* Cp = WF32 ? C + (size_t)z * sC : nullptr;
    u16* Chp = WSPLIT ? Chi + (size_t)z * sC : nullptr;
    u16* Clp = WSPLIT ? Clo + (size_t)z * sC : nullptr;
#pragma unroll
    for (int mi = 0; mi < 4; ++mi) {
#pragma unroll
        for (int rg = 0; rg < 4; ++rg) {
            int row = br + wr + mi * 16 + fq * 4 + rg;
            size_t rb = (size_t)row * Ncols;
#pragma unroll
            for (int ni = 0; ni < 4; ++ni) {
                int col = bc + wc + ni * 16 + fr;
                float v = acc[mi][ni][rg];
                if (BIAS) v += bias[col];
                if (WF32) Cp[rb + col] = v;
                if (WSPLIT) {
                    u16 h = f2b(v);
                    Chp[rb + col] = h;
                    Clp[rb + col] = f2b(v - b2f(h));
                }
            }
        }
    }
}

extern "C" void kernel_launch(void* const* d_in, const int* in_sizes, int n_in,
                              void* d_out, int out_size, void* d_ws, size_t ws_size,
                              hipStream_t stream) {
    const float* x      = (const float*)d_in[0];
    const float* dis    = (const float*)d_in[1];
    const float* ln_w   = (const float*)d_in[2];
    const float* ln_b   = (const float*)d_in[3];
    const float* bn_g   = (const float*)d_in[4];
    const float* bn_b   = (const float*)d_in[5];
    const float* li_w   = (const float*)d_in[6];
    const float* li_b   = (const float*)d_in[7];
    const float* cheb_w = (const float*)d_in[8];
    const float* cheb_b = (const float*)d_in[9];
    float* out = (float*)d_out;

    const size_t BNT = (size_t)Bb * Nn * Td;   // 8388608
    const size_t BNN = (size_t)Bb * Nn * Nn;   // 4194304
    float* ws = (float*)d_ws;
    u16* xhi = (u16*)ws;
    u16* xlo = xhi + BNT;
    u16* xphi = (u16*)(ws + BNT);
    u16* xplo = xphi + BNT;
    u16* cat  = (u16*)(ws + BNT);               // [16384][1536] bf16
    float* sc = ws + 2 * BNT;
    float* p4 = ws + 2 * BNT + BNN;
    u16* bufB = (u16*)p4;                        // BNT u16 (Tx^T scratch)
    float* p5 = p4 + BNT / 2;
    u16* bA = (u16*)p5;                          // BNN u16
    float* p6 = p5 + BNN / 2;
    u16* bWc = (u16*)p6;                         // 512*1536 u16
    float* p7 = p6 + (512 * 1536) / 2;
    u16* liwhi = (u16*)p7;                       // 512*512 u16 x2
    u16* liwlo = liwhi + 512 * 512;
    float* p8 = p7 + 262144;
    float* dinv = p8;                            // 16384
    float2* part = (float2*)(dinv + 16384);      // 4096 floats

    // 1. LayerNorm stage A, then apply (finalize fused) -> hi/lo split
    hipLaunchKernelGGL(ln_partial_k, dim3(32, Bb), dim3(256), 0, stream, (const float4*)x, part);
    hipLaunchKernelGGL(ln_apply_split_k, dim3(BNT / 1024), dim3(256), 0, stream,
                       (const float4*)x, (const float4*)ln_w, (const float4*)ln_b, part,
                       (uint2*)xhi, (uint2*)xlo);
    // 1b. param prep: cheb_w^T -> bWc; li_w hi/lo split
    hipLaunchKernelGGL(param_prep_k, dim3(16, 16, 4), dim3(256), 0, stream,
                       cheb_w, bWc, li_w, liwhi, liwlo);
    // 2. xp = x_ln @ li_w^T + li_b  (split-bf16 3-MFMA -> hi/lo)
    hipLaunchKernelGGL((gemm_bf3_k<true, true, false>), dim3(Bb * Nn / 128, Td / 128, 1), dim3(256), 0, stream,
                       xhi, xlo, liwhi, liwlo, li_b, (float*)nullptr, xphi, xplo,
                       Td, Td, 0LL, 0LL, 0LL);
    // 3. scores[b] = xp[b] @ xp[b]^T  (split-bf16 -> fp32)
    hipLaunchKernelGGL((gemm_bf3_k<false, false, true>), dim3(Nn / 128, Nn / 128, Bb), dim3(256), 0, stream,
                       xphi, xplo, xphi, xplo, (const float*)nullptr, sc, (u16*)nullptr, (u16*)nullptr,
                       Nn, Td, (long long)Nn * Td, (long long)Nn * Td, (long long)Nn * Nn);
    // 4. top-k radix-select; A = relu(A_s + dis) -> bf16 bA; dinv
    hipLaunchKernelGGL(topk_sel_k, dim3(Bb * Nn), dim3(256), 0, stream, sc, dis, bA, dinv);
    // 5. BatchNorm stage A, then apply (finalize fused) -> concat cols [0,512)  (Tx0)
    hipLaunchKernelGGL(bn_partial_k, dim3(8, Nn), dim3(256), 0, stream,
                       (const uint2*)xhi, (const uint2*)xlo, part);
    hipLaunchKernelGGL(bn_apply_cast_k, dim3(BNT / 1024), dim3(256), 0, stream,
                       (const uint2*)xhi, (const uint2*)xlo, part, bn_g, bn_b, (uint2*)cat);
    // 6. bufB[b][t][m] = Tx0[b][m][t] * d[b][m]
    hipLaunchKernelGGL(tscale_k, dim3(16, 8, Bb), dim3(256), 0, stream,
                       cat, bufB, (long long)Nn * 1536, 1536, (long long)Td * Nn, Nn,
                       dinv, Nn);
    // 7. Tx1 = d*(A @ (d*Tx0)) -> concat cols [512,1024)
    hipLaunchKernelGGL((gemm_bf_k<false, false, true, false, true>), dim3(Nn / 128, Td / 128, Bb), dim3(256), 0, stream,
                       bA, bufB, (const float*)nullptr, (const u16*)nullptr, 0,
                       (float*)nullptr, cat + 512, 1536, dinv, Nn,
                       1.0f, Td, Nn, (long long)Nn * Nn, (long long)Td * Nn, 0LL, 0LL,
                       (long long)Nn * 1536);
    // 8. bufB[b][t][m] = Tx1[b][m][t] * d[b][m]
    hipLaunchKernelGGL(tscale_k, dim3(16, 8, Bb), dim3(256), 0, stream,
                       cat + 512, bufB, (long long)Nn * 1536, 1536, (long long)Td * Nn, Nn,
                       dinv, Nn);
    // 9. Tx2 = 2*d*(A @ (d*Tx1)) - Tx0 -> concat cols [1024,1536)
    hipLaunchKernelGGL((gemm_bf_k<false, true, true, false, true>), dim3(Nn / 128, Td / 128, Bb), dim3(256), 0, stream,
                       bA, bufB, (const float*)nullptr, cat, 1536,
                       (float*)nullptr, cat + 1024, 1536, dinv, Nn,
                       2.0f, Td, Nn, (long long)Nn * Nn, (long long)Td * Nn, (long long)Nn * 1536, 0LL,
                       (long long)Nn * 1536);
    // 10. out = relu([Tx0|Tx1|Tx2] @ [W0;W1;W2]^T + cheb_b)   (K=1536)
    hipLaunchKernelGGL((gemm_bf_k<true, false, false, true, false>), dim3(Bb * Nn / 128, Td / 128, 1), dim3(256), 0, stream,
                       cat, bWc, cheb_b, (const u16*)nullptr, 0,
                       out, (u16*)nullptr, 0, (const float*)nullptr, 0,
                       1.0f, Td, 1536, 0LL, 0LL, 0LL, 0LL, 0LL);
}

// Round 11
// 319.240 us; speedup vs baseline: 1.0911x; 1.0911x over previous
//
#include <hip/hip_runtime.h>
#include <cstddef>

static constexpr int Bb = 64;     // batch
static constexpr int Nn = 256;    // nodes
static constexpr int Td = 512;    // time dim
static constexpr int NMAXS = 51;  // 256 // 5
static constexpr float EPSN = 1e-5f;
static constexpr float EPSD = 1e-10f;

typedef unsigned short u16;
typedef __attribute__((ext_vector_type(8))) short short8;
typedef __attribute__((ext_vector_type(4))) float f32x4;

__device__ __forceinline__ u16 f2b(float f) {
    unsigned u = __float_as_uint(f);
    return (u16)((u + 0x7fffu + ((u >> 16) & 1u)) >> 16);
}
__device__ __forceinline__ float b2f(u16 h) {
    return __uint_as_float(((unsigned)h) << 16);
}
__device__ __forceinline__ float4 unp2(uint2 h, uint2 l) {
    float4 r;
    r.x = b2f((u16)h.x) + b2f((u16)l.x);
    r.y = b2f((u16)(h.x >> 16)) + b2f((u16)(l.x >> 16));
    r.z = b2f((u16)h.y) + b2f((u16)l.y);
    r.w = b2f((u16)(h.y >> 16)) + b2f((u16)(l.y >> 16));
    return r;
}

// async global->LDS DMA, 16B/lane. LDS dest = wave-uniform base + lane*16.
__device__ __forceinline__ void gload_lds(const u16* g, u16* l) {
    __builtin_amdgcn_global_load_lds(
        (const __attribute__((address_space(1))) unsigned int*)g,
        (__attribute__((address_space(3))) unsigned int*)l, 16, 0, 0);
}
__device__ __forceinline__ int swz4(int r) { return (r ^ (r >> 2)) & 3; }

// ---------------- LayerNorm stats stage A ----------------
__global__ __launch_bounds__(256) void ln_partial_k(const float4* __restrict__ x,
                                                    float2* __restrict__ part) {
    int b = blockIdx.y, c = blockIdx.x;
    int base = b * 32768 + c * 1024;
    float s = 0.f, s2 = 0.f;
#pragma unroll
    for (int j = 0; j < 4; ++j) {
        float4 v = x[base + j * 256 + threadIdx.x];
        s += v.x + v.y + v.z + v.w;
        s2 += v.x * v.x + v.y * v.y + v.z * v.z + v.w * v.w;
    }
    __shared__ float sh[256], sh2[256];
    sh[threadIdx.x] = s; sh2[threadIdx.x] = s2;
    __syncthreads();
    for (int o = 128; o > 0; o >>= 1) {
        if (threadIdx.x < o) { sh[threadIdx.x] += sh[threadIdx.x + o]; sh2[threadIdx.x] += sh2[threadIdx.x + o]; }
        __syncthreads();
    }
    if (threadIdx.x == 0) part[b * 32 + c] = make_float2(sh[0], sh2[0]);
}

// LN apply (finalize fused via shfl over 32 partials): hi/lo bf16 split out
__global__ __launch_bounds__(256) void ln_apply_split_k(const float4* __restrict__ x,
                                                        const float4* __restrict__ w,
                                                        const float4* __restrict__ bia,
                                                        const float2* __restrict__ part,
                                                        uint2* __restrict__ xhi,
                                                        uint2* __restrict__ xlo) {
    int i = blockIdx.x * 256 + threadIdx.x;
    int r = i & ((Nn * Td / 4) - 1);
    int b = i >> 15;
    float2 p = part[b * 32 + (threadIdx.x & 31)];
    float s = p.x, s2 = p.y;
#pragma unroll
    for (int o = 16; o > 0; o >>= 1) { s += __shfl_xor(s, o, 32); s2 += __shfl_xor(s2, o, 32); }
    float inv = 1.f / (Nn * Td);
    float mu = s * inv;
    float var = s2 * inv - mu * mu;
    float rs = rsqrtf(var + EPSN);
    float4 xv = x[i], wv = w[r], bv = bia[r];
    float4 o;
    o.x = (xv.x - mu) * rs * wv.x + bv.x;
    o.y = (xv.y - mu) * rs * wv.y + bv.y;
    o.z = (xv.z - mu) * rs * wv.z + bv.z;
    o.w = (xv.w - mu) * rs * wv.w + bv.w;
    u16 hx = f2b(o.x), hy = f2b(o.y), hz = f2b(o.z), hw = f2b(o.w);
    uint2 ph, pl;
    ph.x = (unsigned)hx | ((unsigned)hy << 16);
    ph.y = (unsigned)hz | ((unsigned)hw << 16);
    pl.x = (unsigned)f2b(o.x - b2f(hx)) | ((unsigned)f2b(o.y - b2f(hy)) << 16);
    pl.y = (unsigned)f2b(o.z - b2f(hz)) | ((unsigned)f2b(o.w - b2f(hw)) << 16);
    xhi[i] = ph;
    xlo[i] = pl;
}

// ---------------- param prep: cheb_w^T -> bWc (z<3) ; li_w hi/lo split (z==3) ----------------
__global__ __launch_bounds__(256) void param_prep_k(const float* __restrict__ cheb_w,
                                                    u16* __restrict__ bWc,
                                                    const float* __restrict__ li_w,
                                                    u16* __restrict__ liwhi,
                                                    u16* __restrict__ liwlo) {
    int z = blockIdx.z;
    int c0 = blockIdx.x * 32, r0 = blockIdx.y * 32;
    int tx = threadIdx.x & 31, ty = threadIdx.x >> 5;
    if (z < 3) {
        __shared__ u16 tile[32][33];
        const float* ip = cheb_w + (size_t)z * Td * Td;
#pragma unroll
        for (int i = 0; i < 4; ++i) {
            int r = ty + i * 8;
            tile[r][tx] = f2b(ip[(size_t)(r0 + r) * Td + c0 + tx]);
        }
        __syncthreads();
#pragma unroll
        for (int i = 0; i < 4; ++i) {
            int c = ty + i * 8;
            bWc[(size_t)(c0 + c) * 1536 + z * 512 + (r0 + tx)] = tile[tx][c];
        }
    } else {
#pragma unroll
        for (int i = 0; i < 4; ++i) {
            int r = r0 + ty + i * 8;
            size_t idx = (size_t)r * Td + c0 + tx;
            float v = li_w[idx];
            u16 h = f2b(v);
            liwhi[idx] = h;
            liwlo[idx] = f2b(v - b2f(h));
        }
    }
}

// ---------------- BatchNorm stats stage A (from hi/lo split) ----------------
__global__ __launch_bounds__(256) void bn_partial_k(const uint2* __restrict__ xhi,
                                                    const uint2* __restrict__ xlo,
                                                    float2* __restrict__ part) {
    int n = blockIdx.y, c = blockIdx.x;
    float s = 0.f, s2 = 0.f;
#pragma unroll
    for (int j = 0; j < 4; ++j) {
        int f = j * 256 + threadIdx.x;
        int bl = f >> 7, t4 = f & 127;
        size_t idx = ((size_t)(c * 8 + bl) * Nn + n) * 128 + t4;
        float4 v = unp2(xhi[idx], xlo[idx]);
        s += v.x + v.y + v.z + v.w;
        s2 += v.x * v.x + v.y * v.y + v.z * v.z + v.w * v.w;
    }
    __shared__ float sh[256], sh2[256];
    sh[threadIdx.x] = s; sh2[threadIdx.x] = s2;
    __syncthreads();
    for (int o = 128; o > 0; o >>= 1) {
        if (threadIdx.x < o) { sh[threadIdx.x] += sh[threadIdx.x + o]; sh2[threadIdx.x] += sh2[threadIdx.x + o]; }
        __syncthreads();
    }
    if (threadIdx.x == 0) part[n * 8 + c] = make_float2(sh[0], sh2[0]);
}

// BN apply (finalize fused via shfl over 8 partials); writes Tx0 bf16 into cat[.,0:512]
__global__ __launch_bounds__(256) void bn_apply_cast_k(const uint2* __restrict__ xhi,
                                                       const uint2* __restrict__ xlo,
                                                       const float2* __restrict__ part,
                                                       const float* __restrict__ g,
                                                       const float* __restrict__ be,
                                                       uint2* __restrict__ cat) {
    int i = blockIdx.x * 256 + threadIdx.x;   // uint2 index over BNT/4
    int row = i >> 7, c4 = i & 127;
    int n = row & 255;
    float2 p = part[n * 8 + (threadIdx.x & 7)];
    float s = p.x, s2 = p.y;
#pragma unroll
    for (int o = 4; o > 0; o >>= 1) { s += __shfl_xor(s, o, 8); s2 += __shfl_xor(s2, o, 8); }
    float inv = 1.f / (Bb * Td);
    float mu = s * inv;
    float var = s2 * inv - mu * mu;
    float rs = rsqrtf(var + EPSN);
    float scale = rs * g[n];
    float shift = be[n] - mu * scale;
    float4 v = unp2(xhi[i], xlo[i]);
    v.x = v.x * scale + shift; v.y = v.y * scale + shift;
    v.z = v.z * scale + shift; v.w = v.w * scale + shift;
    uint2 o2;
    o2.x = (unsigned)f2b(v.x) | ((unsigned)f2b(v.y) << 16);
    o2.y = (unsigned)f2b(v.z) | ((unsigned)f2b(v.w) << 16);
    cat[(size_t)row * 384 + c4] = o2;   // 1536 u16 = 384 uint2 per row
}

// ---------------- top-k radix-select + adjacency; writes bf16 A + dinv ----------------
__global__ __launch_bounds__(256) void topk_sel_k(const float* __restrict__ sc,
                                                  const float* __restrict__ dis,
                                                  u16* __restrict__ bA,
                                                  float* __restrict__ dinv) {
    int row = blockIdx.x;
    int n = row & 255;
    int tid = threadIdx.x;
    int lane = tid & 63, wv = tid >> 6;
    const float* srow = sc + (size_t)row * Nn;
    float v = srow[tid];
    unsigned fu = __float_as_uint(v);
    unsigned key = (fu & 0x80000000u) ? ~fu : (fu | 0x80000000u);
    __shared__ int hist[256];
    __shared__ int cum[256];
    __shared__ unsigned sh_pref;
    __shared__ int sh_rank;
    __shared__ float wsum[4];
    if (tid == 0) { sh_pref = 0u; sh_rank = Nn - NMAXS; }  // 205
    __syncthreads();
#pragma unroll
    for (int shift = 24; shift >= 0; shift -= 8) {
        unsigned mhi = (shift == 24) ? 0u : (0xFFFFFFFFu << (shift + 8));
        unsigned pref = sh_pref;
        int rank = sh_rank;
        hist[tid] = 0;
        __syncthreads();
        if ((key & mhi) == pref) atomicAdd(&hist[(key >> shift) & 255], 1);
        __syncthreads();
        if (tid < 64) {
            int4 h = *(const int4*)&hist[tid * 4];
            int s0 = h.x, s1 = s0 + h.y, s2 = s1 + h.z, s3 = s2 + h.w;
            int t = s3;
#pragma unroll
            for (int o = 1; o < 64; o <<= 1) { int y = __shfl_up(t, o, 64); if (lane >= o) t += y; }
            int excl = t - s3;
            cum[tid * 4]     = excl + s0;
            cum[tid * 4 + 1] = excl + s1;
            cum[tid * 4 + 2] = excl + s2;
            cum[tid * 4 + 3] = excl + s3;
        }
        __syncthreads();
        int below = (tid == 0) ? 0 : cum[tid - 1];
        if (cum[tid] > rank && below <= rank) {
            sh_pref = pref | ((unsigned)tid << shift);
            sh_rank = rank - below;
        }
        __syncthreads();
    }
    unsigned kk = sh_pref;
    float kth = __uint_as_float((kk & 0x80000000u) ? (kk & 0x7FFFFFFFu) : ~kk);
    float as = (v >= kth) ? v : 0.f;
    float a = fmaxf(as + dis[(size_t)n * Nn + tid], 0.f);
    bA[(size_t)row * Nn + tid] = f2b(a);
    float s = a;
#pragma unroll
    for (int o = 32; o > 0; o >>= 1) s += __shfl_down(s, o, 64);
    if (lane == 0) wsum[wv] = s;
    __syncthreads();
    if (tid == 0) dinv[row] = rsqrtf(wsum[0] + wsum[1] + wsum[2] + wsum[3] + EPSD);
}

// ---------------- transpose u16 (+per-input-row scale) ----------------
__global__ __launch_bounds__(256) void tscale_k(const u16* __restrict__ in,
                                                u16* __restrict__ out,
                                                long long ibz, int ildr,
                                                long long obz, int oldr,
                                                const float* __restrict__ rs, int rsz) {
    __shared__ u16 tile[32][33];
    int b = blockIdx.z;
    int c0 = blockIdx.x * 32, r0 = blockIdx.y * 32;
    int tx = threadIdx.x & 31, ty = threadIdx.x >> 5;
#pragma unroll
    for (int i = 0; i < 4; ++i) {
        int r = ty + i * 8;
        float f = b2f(in[(size_t)b * ibz + (size_t)(r0 + r) * ildr + c0 + tx]);
        f *= rs[b * rsz + r0 + r];
        tile[r][tx] = f2b(f);
    }
    __syncthreads();
#pragma unroll
    for (int i = 0; i < 4; ++i) {
        int c = ty + i * 8;
        out[(size_t)b * obz + (size_t)(c0 + c) * oldr + (r0 + tx)] = tile[tx][c];
    }
}

// ---------------- bf16 MFMA GEMM, NT, 128x64 tile, BK=64, DMA dbuf ----------------
// Both A and B staged via global_load_lds (R8 structure). N-tile 64 -> grid 1024,
// LDS 48KB -> 3 blocks/CU = 3 waves/SIMD (vs R8's 2). MFMA order per output
// element unchanged -> bit-identical results.
template <bool FINAL, bool SUBPREV, bool RSCALE, bool WF32, bool WBF>
__global__ __launch_bounds__(256) void gemm_bf_k(const u16* __restrict__ A,
                                                 const u16* __restrict__ Bt,
                                                 const float* __restrict__ bias,
                                                 const u16* __restrict__ prevb, int ldprev,
                                                 float* __restrict__ C,
                                                 u16* __restrict__ Cb, int ldcb,
                                                 const float* __restrict__ rscale, int rsz,
                                                 float alpha, int Ncols, int K,
                                                 long long sA, long long sB, long long sPrev,
                                                 long long sC, long long sCb) {
    __shared__ u16 As[2][8192];   // [buf][h*4096 + row*32 + chunk]  128 rows
    __shared__ u16 Bs[2][4096];   // [buf][h*2048 + row*32 + chunk]   64 rows
    int z = blockIdx.z;
    const u16* Ag = A + (size_t)z * sA;
    const u16* Bg = Bt + (size_t)z * sB;
    int br = blockIdx.x * 128, bc = blockIdx.y * 64;
    int tid = threadIdx.x, lane = tid & 63, wave = tid >> 6;
    int wr = (wave >> 1) * 64, wc = (wave & 1) * 32;
    int i0 = wave * 2;
    // A staging rows (2 DMA instrs per wave per h)
    int rl0 = i0 * 16 + (lane >> 2);
    int rl1 = rl0 + 16;
    int cp = lane & 3;
    int ca0 = (cp ^ swz4(rl0)) * 8;
    int ca1 = (cp ^ swz4(rl1)) * 8;
    const u16* gA0 = Ag + (size_t)(br + rl0) * K + ca0;
    const u16* gA1 = Ag + (size_t)(br + rl1) * K + ca1;
    // B staging rows (1 DMA instr per wave per h): rows [16w, 16w+16)
    int rbw = wave * 16 + (lane >> 2);
    int cb = (cp ^ swz4(rbw)) * 8;
    const u16* gB0 = Bg + (size_t)(bc + rbw) * K + cb;
    f32x4 acc[4][2] = {};
    int fr = lane & 15, fq = lane >> 4;
    auto stage = [&](int buf, int k0) {
#pragma unroll
        for (int h = 0; h < 2; ++h) {
            int kk = k0 + h * 32;
            gload_lds(gA0 + kk, &As[buf][h * 4096 + i0 * 512]);
            gload_lds(gA1 + kk, &As[buf][h * 4096 + i0 * 512 + 512]);
            gload_lds(gB0 + kk, &Bs[buf][h * 2048 + wave * 512]);
        }
    };
    int nIter = K >> 6;
    stage(0, 0);
    for (int it = 0; it < nIter; ++it) {
        int cur = it & 1;
        __syncthreads();                       // drains stage issued one compute-phase ago
        if (it + 1 < nIter) stage(1 - cur, (it + 1) << 6);
#pragma unroll
        for (int h = 0; h < 2; ++h) {
            short8 af[4], bf[2];
#pragma unroll
            for (int mi = 0; mi < 4; ++mi) {
                int rr = wr + mi * 16 + fr;
                af[mi] = *(const short8*)&As[cur][h * 4096 + rr * 32 + ((fq ^ swz4(rr)) << 3)];
            }
#pragma unroll
            for (int ni = 0; ni < 2; ++ni) {
                int rr = wc + ni * 16 + fr;
                bf[ni] = *(const short8*)&Bs[cur][h * 2048 + rr * 32 + ((fq ^ swz4(rr)) << 3)];
            }
#pragma unroll
            for (int mi = 0; mi < 4; ++mi)
#pragma unroll
                for (int ni = 0; ni < 2; ++ni)
                    acc[mi][ni] = __builtin_amdgcn_mfma_f32_16x16x32_bf16(af[mi], bf[ni], acc[mi][ni], 0, 0, 0);
        }
    }
    const u16* Pp = SUBPREV ? prevb + (size_t)z * sPrev : nullptr;
    float* Cp = WF32 ? C + (size_t)z * sC : nullptr;
    u16* Cbp = WBF ? Cb + (size_t)z * sCb : nullptr;
    const float* rsp = RSCALE ? rscale + (size_t)z * rsz : nullptr;
#pragma unroll
    for (int mi = 0; mi < 4; ++mi) {
#pragma unroll
        for (int rg = 0; rg < 4; ++rg) {
            int row = br + wr + mi * 16 + fq * 4 + rg;
            float rowsc = RSCALE ? rsp[row] : 1.f;
#pragma unroll
            for (int ni = 0; ni < 2; ++ni) {
                int col = bc + wc + ni * 16 + fr;
                float v = alpha * acc[mi][ni][rg];
                if (RSCALE) v *= rowsc;
                if (SUBPREV) v -= b2f(Pp[(size_t)row * ldprev + col]);
                if (FINAL) v = fmaxf(v + bias[col], 0.f);
                if (WF32) Cp[(size_t)row * Ncols + col] = v;
                if (WBF) Cbp[(size_t)row * ldcb + col] = f2b(v);
            }
        }
    }
}

// ---------------- split-bf16 3-MFMA GEMM, NT, DMA + double-buffered prefetch, BK=32 (R8) ----------------
template <bool BIAS, bool WSPLIT, bool WF32>
__global__ __launch_bounds__(256) void gemm_bf3_k(const u16* __restrict__ Ahi,
                                                  const u16* __restrict__ Alo,
                                                  const u16* __restrict__ Bhi,
                                                  const u16* __restrict__ Blo,
                                                  const float* __restrict__ bias,
                                                  float* __restrict__ C,
                                                  u16* __restrict__ Chi,
                                                  u16* __restrict__ Clo,
                                                  int Ncols, int K,
                                                  long long sA, long long sB, long long sC) {
    __shared__ u16 Ash[2][4096];
    __shared__ u16 Asl[2][4096];
    __shared__ u16 Bsh[2][4096];
    __shared__ u16 Bsl[2][4096];
    int z = blockIdx.z;
    const u16* Agh = Ahi + (size_t)z * sA;
    const u16* Agl = Alo + (size_t)z * sA;
    const u16* Bgh = Bhi + (size_t)z * sB;
    const u16* Bgl = Blo + (size_t)z * sB;
    int br = blockIdx.x * 128, bc = blockIdx.y * 128;
    int tid = threadIdx.x, lane = tid & 63, wave = tid >> 6;
    int wr = (wave >> 1) * 64, wc = (wave & 1) * 64;
    int i0 = wave * 2;
    int rl0 = i0 * 16 + (lane >> 2);
    int rl1 = rl0 + 16;
    int cp = lane & 3;
    int ca0 = (cp ^ swz4(rl0)) * 8;
    int ca1 = (cp ^ swz4(rl1)) * 8;
    size_t oA0 = (size_t)(br + rl0) * K + ca0;
    size_t oA1 = (size_t)(br + rl1) * K + ca1;
    size_t oB0 = (size_t)(bc + rl0) * K + ca0;
    size_t oB1 = (size_t)(bc + rl1) * K + ca1;
    f32x4 acc[4][4] = {};
    int fr = lane & 15, fq = lane >> 4;
    auto stage = [&](int buf, int kk) {
        gload_lds(Agh + oA0 + kk, &Ash[buf][i0 * 512]);
        gload_lds(Agh + oA1 + kk, &Ash[buf][i0 * 512 + 512]);
        gload_lds(Agl + oA0 + kk, &Asl[buf][i0 * 512]);
        gload_lds(Agl + oA1 + kk, &Asl[buf][i0 * 512 + 512]);
        gload_lds(Bgh + oB0 + kk, &Bsh[buf][i0 * 512]);
        gload_lds(Bgh + oB1 + kk, &Bsh[buf][i0 * 512 + 512]);
        gload_lds(Bgl + oB0 + kk, &Bsl[buf][i0 * 512]);
        gload_lds(Bgl + oB1 + kk, &Bsl[buf][i0 * 512 + 512]);
    };
    int nIter = K >> 5;
    stage(0, 0);
    for (int it = 0; it < nIter; ++it) {
        int cur = it & 1;
        __syncthreads();
        if (it + 1 < nIter) stage(1 - cur, (it + 1) << 5);
        short8 afh[4], afl[4], bfh[4], bfl[4];
#pragma unroll
        for (int mi = 0; mi < 4; ++mi) {
            int rr = wr + mi * 16 + fr;
            int off = rr * 32 + ((fq ^ swz4(rr)) << 3);
            afh[mi] = *(const short8*)&Ash[cur][off];
            afl[mi] = *(const short8*)&Asl[cur][off];
        }
#pragma unroll
        for (int ni = 0; ni < 4; ++ni) {
            int rr = wc + ni * 16 + fr;
            int off = rr * 32 + ((fq ^ swz4(rr)) << 3);
            bfh[ni] = *(const short8*)&Bsh[cur][off];
            bfl[ni] = *(const short8*)&Bsl[cur][off];
        }
#pragma unroll
        for (int mi = 0; mi < 4; ++mi)
#pragma unroll
            for (int ni = 0; ni < 4; ++ni) {
                acc[mi][ni] = __builtin_amdgcn_mfma_f32_16x16x32_bf16(afh[mi], bfh[ni], acc[mi][ni], 0, 0, 0);
                acc[mi][ni] = __builtin_amdgcn_mfma_f32_16x16x32_bf16(afh[mi], bfl[ni], acc[mi][ni], 0, 0, 0);
                acc[mi][ni] = __builtin_amdgcn_mfma_f32_16x16x32_bf16(afl[mi], bfh[ni], acc[mi][ni], 0, 0, 0);
            }
    }
    float* Cp = WF32 ? C + (size_t)z * sC : nullptr;
    u16* Chp = WSPLIT ? Chi + (size_t)z * sC : nullptr;
    u16* Clp = WSPLIT ? Clo + (size_t)z * sC : nullptr;
#pragma unroll
    for (int mi = 0; mi < 4; ++mi) {
#pragma unroll
        for (int rg = 0; rg < 4; ++rg) {
            int row = br + wr + mi * 16 + fq * 4 + rg;
            size_t rb = (size_t)row * Ncols;
#pragma unroll
            for (int ni = 0; ni < 4; ++ni) {
                int col = bc + wc + ni * 16 + fr;
                float v = acc[mi][ni][rg];
                if (BIAS) v += bias[col];
                if (WF32) Cp[rb + col] = v;
                if (WSPLIT) {
                    u16 h = f2b(v);
                    Chp[rb + col] = h;
                    Clp[rb + col] = f2b(v - b2f(h));
                }
            }
        }
    }
}

extern "C" void kernel_launch(void* const* d_in, const int* in_sizes, int n_in,
                              void* d_out, int out_size, void* d_ws, size_t ws_size,
                              hipStream_t stream) {
    const float* x      = (const float*)d_in[0];
    const float* dis    = (const float*)d_in[1];
    const float* ln_w   = (const float*)d_in[2];
    const float* ln_b   = (const float*)d_in[3];
    const float* bn_g   = (const float*)d_in[4];
    const float* bn_b   = (const float*)d_in[5];
    const float* li_w   = (const float*)d_in[6];
    const float* li_b   = (const float*)d_in[7];
    const float* cheb_w = (const float*)d_in[8];
    const float* cheb_b = (const float*)d_in[9];
    float* out = (float*)d_out;

    const size_t BNT = (size_t)Bb * Nn * Td;   // 8388608
    const size_t BNN = (size_t)Bb * Nn * Nn;   // 4194304
    float* ws = (float*)d_ws;
    u16* xhi = (u16*)ws;
    u16* xlo = xhi + BNT;
    u16* xphi = (u16*)(ws + BNT);
    u16* xplo = xphi + BNT;
    u16* cat  = (u16*)(ws + BNT);               // [16384][1536] bf16
    float* sc = ws + 2 * BNT;
    float* p4 = ws + 2 * BNT + BNN;
    u16* bufB = (u16*)p4;                        // BNT u16 (Tx^T scratch)
    float* p5 = p4 + BNT / 2;
    u16* bA = (u16*)p5;                          // BNN u16
    float* p6 = p5 + BNN / 2;
    u16* bWc = (u16*)p6;                         // 512*1536 u16
    float* p7 = p6 + (512 * 1536) / 2;
    u16* liwhi = (u16*)p7;                       // 512*512 u16 x2
    u16* liwlo = liwhi + 512 * 512;
    float* p8 = p7 + 262144;
    float* dinv = p8;                            // 16384
    float2* part = (float2*)(dinv + 16384);      // 4096 floats

    // 1. LayerNorm stage A, then apply (finalize fused) -> hi/lo split
    hipLaunchKernelGGL(ln_partial_k, dim3(32, Bb), dim3(256), 0, stream, (const float4*)x, part);
    hipLaunchKernelGGL(ln_apply_split_k, dim3(BNT / 1024), dim3(256), 0, stream,
                       (const float4*)x, (const float4*)ln_w, (const float4*)ln_b, part,
                       (uint2*)xhi, (uint2*)xlo);
    // 1b. param prep: cheb_w^T -> bWc; li_w hi/lo split
    hipLaunchKernelGGL(param_prep_k, dim3(16, 16, 4), dim3(256), 0, stream,
                       cheb_w, bWc, li_w, liwhi, liwlo);
    // 2. xp = x_ln @ li_w^T + li_b  (split-bf16 3-MFMA -> hi/lo)
    hipLaunchKernelGGL((gemm_bf3_k<true, true, false>), dim3(Bb * Nn / 128, Td / 128, 1), dim3(256), 0, stream,
                       xhi, xlo, liwhi, liwlo, li_b, (float*)nullptr, xphi, xplo,
                       Td, Td, 0LL, 0LL, 0LL);
    // 3. scores[b] = xp[b] @ xp[b]^T  (split-bf16 -> fp32)
    hipLaunchKernelGGL((gemm_bf3_k<false, false, true>), dim3(Nn / 128, Nn / 128, Bb), dim3(256), 0, stream,
                       xphi, xplo, xphi, xplo, (const float*)nullptr, sc, (u16*)nullptr, (u16*)nullptr,
                       Nn, Td, (long long)Nn * Td, (long long)Nn * Td, (long long)Nn * Nn);
    // 4. top-k radix-select; A = relu(A_s + dis) -> bf16 bA; dinv
    hipLaunchKernelGGL(topk_sel_k, dim3(Bb * Nn), dim3(256), 0, stream, sc, dis, bA, dinv);
    // 5. BatchNorm stage A, then apply (finalize fused) -> concat cols [0,512)  (Tx0)
    hipLaunchKernelGGL(bn_partial_k, dim3(8, Nn), dim3(256), 0, stream,
                       (const uint2*)xhi, (const uint2*)xlo, part);
    hipLaunchKernelGGL(bn_apply_cast_k, dim3(BNT / 1024), dim3(256), 0, stream,
                       (const uint2*)xhi, (const uint2*)xlo, part, bn_g, bn_b, (uint2*)cat);
    // 6. bufB[b][t][m] = Tx0[b][m][t] * d[b][m]
    hipLaunchKernelGGL(tscale_k, dim3(16, 8, Bb), dim3(256), 0, stream,
                       cat, bufB, (long long)Nn * 1536, 1536, (long long)Td * Nn, Nn,
                       dinv, Nn);
    // 7. Tx1 = d*(A @ (d*Tx0)) -> concat cols [512,1024)
    hipLaunchKernelGGL((gemm_bf_k<false, false, true, false, true>), dim3(Nn / 128, Td / 64, Bb), dim3(256), 0, stream,
                       bA, bufB, (const float*)nullptr, (const u16*)nullptr, 0,
                       (float*)nullptr, cat + 512, 1536, dinv, Nn,
                       1.0f, Td, Nn, (long long)Nn * Nn, (long long)Td * Nn, 0LL, 0LL,
                       (long long)Nn * 1536);
    // 8. bufB[b][t][m] = Tx1[b][m][t] * d[b][m]
    hipLaunchKernelGGL(tscale_k, dim3(16, 8, Bb), dim3(256), 0, stream,
                       cat + 512, bufB, (long long)Nn * 1536, 1536, (long long)Td * Nn, Nn,
                       dinv, Nn);
    // 9. Tx2 = 2*d*(A @ (d*Tx1)) - Tx0 -> concat cols [1024,1536)
    hipLaunchKernelGGL((gemm_bf_k<false, true, true, false, true>), dim3(Nn / 128, Td / 64, Bb), dim3(256), 0, stream,
                       bA, bufB, (const float*)nullptr, cat, 1536,
                       (float*)nullptr, cat + 1024, 1536, dinv, Nn,
                       2.0f, Td, Nn, (long long)Nn * Nn, (long long)Td * Nn, (long long)Nn * 1536, 0LL,
                       (long long)Nn * 1536);
    // 10. out = relu([Tx0|Tx1|Tx2] @ [W0;W1;W2]^T + cheb_b)   (K=1536)
    hipLaunchKernelGGL((gemm_bf_k<true, false, false, true, false>), dim3(Bb * Nn / 128, Td / 64, 1), dim3(256), 0, stream,
                       cat, bWc, cheb_b, (const u16*)nullptr, 0,
                       out, (u16*)nullptr, 0, (const float*)nullptr, 0,
                       1.0f, Td, 1536, 0LL, 0LL, 0LL, 0LL, 0LL);
}